// Round 17
// baseline (99.877 us; speedup 1.0000x reference)
//
#include <hip/hip_runtime.h>
#include <hip/hip_bf16.h>
#include <cstddef>

typedef unsigned int uint;
typedef unsigned short ushort_t;
typedef __attribute__((ext_vector_type(8))) short bf16x8;
typedef __attribute__((ext_vector_type(8))) _Float16 f16x8;
typedef __attribute__((ext_vector_type(4))) float f32x4;

constexpr int NB   = 2;
constexpr int NP   = 256;
constexpr int DIM  = 1024;
constexpr int NH   = 16;
constexpr int HD   = 64;
constexpr int SEQ  = 2048;
constexpr int MROW = NB * SEQ;      // 4096
constexpr int N3   = 3 * DIM;       // 3072
// softmax in base-2: fold hd^-0.5 * log2(e) into q
constexpr float QS = 0.125f * 1.4426950408889634f;

__device__ __forceinline__ ushort_t f2bf(float x) {
  uint u = __builtin_bit_cast(uint, x);
  u = (u + 0x7fff + ((u >> 16) & 1)) >> 16;   // round-to-nearest-even
  return (ushort_t)u;
}
__device__ __forceinline__ uint pack_bf16(float a, float b) {
  __hip_bfloat162 h = __float22bfloat162_rn(float2{a, b});
  uint u; __builtin_memcpy(&u, &h, 4);        // v_cvt_pk_bf16_f32
  return u;
}
__device__ __forceinline__ float bf2f(ushort_t h) {
  return __builtin_bit_cast(float, (uint)h << 16);
}
__device__ __forceinline__ ushort_t f2h(float x) {
  _Float16 h = (_Float16)x;
  ushort_t u; __builtin_memcpy(&u, &h, 2);
  return u;
}

template<bool F16>
__device__ __forceinline__ f32x4 mfma16(bf16x8 a, bf16x8 b, f32x4 c) {
  if constexpr (F16) {
    f16x8 af = __builtin_bit_cast(f16x8, a);
    f16x8 bf = __builtin_bit_cast(f16x8, b);
    return __builtin_amdgcn_mfma_f32_16x16x32_f16(af, bf, c, 0, 0, 0);
  } else {
    return __builtin_amdgcn_mfma_f32_16x16x32_bf16(a, b, c, 0, 0, 0);
  }
}

__device__ __forceinline__ void gload16(const void* g, void* l) {
  __builtin_amdgcn_global_load_lds((const __attribute__((address_space(1))) uint*)g,
                                   (__attribute__((address_space(3))) uint*)l, 16, 0, 0);
}

// XCD-aware bijective swizzle (valid when nwg % 8 == 0)
__device__ __forceinline__ uint xcd_swz(uint bid, uint nwg) {
  return (bid & 7) * (nwg >> 3) + (bid >> 3);
}

// ---------------- K0: fused prep: cvt x->bf16, Wqkv->bf16, Wout->f16, RoPE tab
__global__ __launch_bounds__(256) void prep_kernel(
    const float* __restrict__ x, const float* __restrict__ Wqkv,
    const float* __restrict__ Wout, ushort_t* __restrict__ xh,
    ushort_t* __restrict__ wqh, ushort_t* __restrict__ wo16,
    float* __restrict__ tab) {
  const int i = blockIdx.x * 256 + threadIdx.x;
  constexpr int NX = MROW * DIM / 4;   // 1048576
  constexpr int NQ = N3 * DIM / 4;     // 786432
  constexpr int NO = DIM * DIM / 4;    // 262144
  if (i < NX) {
    float4 v = reinterpret_cast<const float4*>(x)[i];
    uint2 o; o.x = pack_bf16(v.x, v.y); o.y = pack_bf16(v.z, v.w);
    reinterpret_cast<uint2*>(xh)[i] = o;
  }
  if (i < NQ) {
    float4 v = reinterpret_cast<const float4*>(Wqkv)[i];
    uint2 o; o.x = pack_bf16(v.x, v.y); o.y = pack_bf16(v.z, v.w);
    reinterpret_cast<uint2*>(wqh)[i] = o;
  }
  if (i < NO) {
    float4 v = reinterpret_cast<const float4*>(Wout)[i];
    uint2 o;
    o.x = (uint)f2h(v.x) | ((uint)f2h(v.y) << 16);
    o.y = (uint)f2h(v.z) | ((uint)f2h(v.w) << 16);
    reinterpret_cast<uint2*>(wo16)[i] = o;
  }
  if (i < SEQ * 32) {
    int l = i >> 5, ii = i & 31;
    float j = (float)(ii & 15);
    float invf = exp2f(-j * (13.287712379549449f / 16.f));
    float pos = (ii < 16) ? (float)(l >> 8) : (float)(l & (NP - 1));
    float ang = pos * invf;
    tab[i]            = cosf(ang);
    tab[SEQ * 32 + i] = sinf(ang);
  }
}

// ---------------- K1: 256x256 8-phase QKV GEMM + fused RMSNorm/RoPE epilogue -
// 8 waves (2m x 4n), BK=64, 2 K-tiles/iter, 8 phases/iter, counted vmcnt(2)
// only at phases 0/4 (T3+T4), setprio around MFMA (T5), LDS 128K (2 slots x
// (A 32K + B 32K)), same XOR-swizzle + pre-swizzled-source machinery as before.
// K-accumulation order per acc element unchanged -> bit-identical output.
__global__ __launch_bounds__(512, 2) void gemm_qkv_kernel(
    const ushort_t* __restrict__ A_, const ushort_t* __restrict__ B_,
    const float* __restrict__ qs, const float* __restrict__ ksc,
    const float* __restrict__ tab, ushort_t* __restrict__ qT,
    ushort_t* __restrict__ kT, ushort_t* __restrict__ vT) {
  __shared__ __align__(16) char smem[131072];
  const int tid = threadIdx.x;
  const int l = tid & 63, w8 = tid >> 6;
  const int l7 = l & 7, l3 = l >> 3, lm = l & 15, lw = l >> 4;
  const int wm = w8 >> 2, wn = w8 & 3;           // 2 x 4 waves
  const uint nwg = gridDim.x * gridDim.y;        // 12*16 = 192
  const uint wg = xcd_swz(blockIdx.y * gridDim.x + blockIdx.x, nwg);
  const int bm = (int)(wg / gridDim.x) * 256, bn = (int)(wg % gridDim.x) * 256;
  const uint rloc = (uint)(w8 * 8 + l3);
  const uint csrc = (uint)((l7 ^ l3) << 4);
  const char* Ab = reinterpret_cast<const char*>(A_);
  const char* Bb = reinterpret_cast<const char*>(B_);

  f32x4 acc[8][4] = {};

  // stage half-tile H (0=A0,1=A1,2=B0,3=B1) of K-tile t into slot s
  auto stageH = [&](int t, int H, int s) {
    const bool isB = H >= 2;
    const int half = H & 1;
    const char* src = isB ? Bb : Ab;
    const int rowg = (isB ? bn : bm) + half * 128;
    char* dst = smem + s * 65536 + (isB ? 32768 : 0) + half * 16384;
#pragma unroll
    for (int inst = 0; inst < 2; ++inst)
      gload16(src + (((size_t)(rowg + inst * 64 + rloc) * DIM + t * 64) << 1) + csrc,
              dst + (inst * 64 + w8 * 8) * 128);
  };

  // prologue: tile 0 fully staged into slot 0
#pragma unroll
  for (int H = 0; H < 4; ++H) stageH(0, H, 0);
  asm volatile("s_waitcnt vmcnt(0)" ::: "memory");
  __builtin_amdgcn_s_barrier();
  __builtin_amdgcn_sched_barrier(0);

  for (int j = 0; j < 8; ++j) {
#pragma unroll
    for (int tt = 0; tt < 2; ++tt) {
      const int t = 2 * j + tt;                  // compute tile (slot = tt)
      const int tst = 2 * j + 1 + tt;            // tile staged this window
      const bool doStage = (tst <= 15);
      const char* As = smem + tt * 65536;
      const char* Bs = As + 32768;
#pragma unroll
      for (int ks = 0; ks < 2; ++ks) {
        bf16x8 bfr[4];
#pragma unroll
        for (int mh = 0; mh < 2; ++mh) {
          const int p = tt * 4 + ks * 2 + mh;    // 0..7
          bf16x8 af[4];
          if (p == 0 || p == 4) {
            // window boundary: stage first, drain previous window's loads
            if (doStage) {
              stageH(tst, p & 3, 1 - tt);
              asm volatile("s_waitcnt vmcnt(2)" ::: "memory");
            } else {
              asm volatile("s_waitcnt vmcnt(0)" ::: "memory");
            }
            __builtin_amdgcn_s_barrier();
            __builtin_amdgcn_sched_barrier(0);
#pragma unroll
            for (int i = 0; i < 4; ++i)
              af[i] = *reinterpret_cast<const bf16x8*>(
                  As + (wm * 128 + (mh * 4 + i) * 16 + lm) * 128 +
                  ((((uint)ks * 4 + lw) ^ (uint)(lm & 7)) << 4));
#pragma unroll
            for (int i = 0; i < 4; ++i)
              bfr[i] = *reinterpret_cast<const bf16x8*>(
                  Bs + (wn * 64 + i * 16 + lm) * 128 +
                  ((((uint)ks * 4 + lw) ^ (uint)(lm & 7)) << 4));
          } else {
#pragma unroll
            for (int i = 0; i < 4; ++i)
              af[i] = *reinterpret_cast<const bf16x8*>(
                  As + (wm * 128 + (mh * 4 + i) * 16 + lm) * 128 +
                  ((((uint)ks * 4 + lw) ^ (uint)(lm & 7)) << 4));
            if (mh == 0)
#pragma unroll
              for (int i = 0; i < 4; ++i)
                bfr[i] = *reinterpret_cast<const bf16x8*>(
                    Bs + (wn * 64 + i * 16 + lm) * 128 +
                    ((((uint)ks * 4 + lw) ^ (uint)(lm & 7)) << 4));
            if (doStage) stageH(tst, p & 3, 1 - tt);
            __builtin_amdgcn_s_barrier();
          }
          __builtin_amdgcn_s_setprio(1);
#pragma unroll
          for (int i = 0; i < 4; ++i)
#pragma unroll
            for (int ni = 0; ni < 4; ++ni)
              acc[mh * 4 + i][ni] = __builtin_amdgcn_mfma_f32_16x16x32_bf16(
                  af[i], bfr[ni], acc[mh * 4 + i][ni], 0, 0, 0);
          __builtin_amdgcn_s_setprio(0);
          __builtin_amdgcn_s_barrier();
        }
      }
    }
  }

  const int sel = bn >> 10;                      // 0=q, 1=k, 2=v
  const int b   = bm >> 11;
  const int l0  = bm & (SEQ - 1);

  if (sel < 2) {
    const float* sc = (sel == 0) ? qs : ksc;
    ushort_t* dst   = (sel == 0) ? qT : kT;
    const int h   = ((bn & (DIM - 1)) >> 6) + wn;
    const int bhI = b * NH + h;
    float scv[4];
#pragma unroll
    for (int ni = 0; ni < 4; ++ni) scv[ni] = sc[ni * 16 + lm];
#pragma unroll
    for (int mi = 0; mi < 8; ++mi)
#pragma unroll
      for (int r = 0; r < 4; ++r) {
        const int lg = l0 + wm * 128 + mi * 16 + lw * 4 + r;
        float c0 = acc[mi][0][r], c1 = acc[mi][1][r];
        float c2 = acc[mi][2][r], c3 = acc[mi][3][r];
        float s = c0 * c0 + c1 * c1 + c2 * c2 + c3 * c3;
        s += __shfl_xor(s, 1); s += __shfl_xor(s, 2);
        s += __shfl_xor(s, 4); s += __shfl_xor(s, 8);
        float rms = rsqrtf(s * (1.f / HD) + 1e-6f);
        float cv[4] = {c0, c1, c2, c3};
#pragma unroll
        for (int ni = 0; ni < 4; ++ni) {
          float n  = cv[ni] * rms * scv[ni];
          float pr = __shfl_xor(n, 1);
          const int jj = ni * 8 + (lm >> 1);
          float cz = tab[lg * 32 + jj];
          float sz = tab[SEQ * 32 + lg * 32 + jj];
          float o = (lm & 1) ? (pr * sz + n * cz) : (n * cz - pr * sz);
          if (sel == 0) o *= QS;
          dst[((size_t)bhI * SEQ + lg) * HD + ni * 16 + lm] = f2bf(o);
        }
      }
  } else {
    // v: two 128-row passes through LDS, then transposed coalesced store
    ushort_t* vt = reinterpret_cast<ushort_t*>(smem);
#pragma unroll
    for (int hf = 0; hf < 2; ++hf) {
      __syncthreads();
      if (wm == hf) {
#pragma unroll
        for (int mi = 0; mi < 8; ++mi)
#pragma unroll
          for (int ni = 0; ni < 4; ++ni)
#pragma unroll
            for (int r = 0; r < 4; ++r)
              vt[(mi * 16 + lw * 4 + r) * 264 + wn * 64 + ni * 16 + lm] =
                  f2bf(acc[mi][ni][r]);
      }
      __syncthreads();
      const int d = tid >> 1, lc0 = (tid & 1) * 64;
      const int hv = ((bn & (DIM - 1)) >> 6) + (d >> 6);
      const int dl = d & 63;
      ushort_t* vp = vT + ((size_t)(b * NH + hv) * HD + dl) * SEQ + l0 + hf * 128 + lc0;
#pragma unroll
      for (int u = 0; u < 8; ++u) {
        ushort_t tmp[8];
#pragma unroll
        for (int jj = 0; jj < 8; ++jj) tmp[jj] = vt[(lc0 + u * 8 + jj) * 264 + d];
        uint4 w;
        w.x = (uint)tmp[0] | ((uint)tmp[1] << 16);
        w.y = (uint)tmp[2] | ((uint)tmp[3] << 16);
        w.z = (uint)tmp[4] | ((uint)tmp[5] << 16);
        w.w = (uint)tmp[6] | ((uint)tmp[7] << 16);
        reinterpret_cast<uint4*>(vp)[u] = w;
      }
    }
  }
}

// ---------------- generic 16-bit MFMA GEMM (out-projection) ------------------
template<int BM, bool BF16OUT, bool F16>
__global__ __launch_bounds__(256) void gemm_mfma_kernel(
    const ushort_t* __restrict__ A_, const ushort_t* __restrict__ B_,
    void* __restrict__ Cv, int N, int K) {
  constexpr int MF = BM / 32;
  constexpr int PH = (BM + 128) * 128;
  __shared__ __align__(16) char smem[2 * PH];
  const int tid = threadIdx.x;
  const int l = tid & 63, w4 = tid >> 6;
  const int l7 = l & 7, l3 = l >> 3, lm = l & 15, lw = l >> 4;
  const int wm = w4 >> 1, wn = w4 & 1;
  const uint nwg = gridDim.x * gridDim.y;
  const uint wg = xcd_swz(blockIdx.y * gridDim.x + blockIdx.x, nwg);
  const int bm = (int)(wg / gridDim.x) * BM, bn = (int)(wg % gridDim.x) * 128;
  const uint rloc = (uint)(w4 * 8 + l3);
  const uint csrc = (uint)((l7 ^ l3) << 4);
  const uint sw = (uint)(lm & 7);

  f32x4 acc[MF][4] = {};

  auto stageAB = [&](int dstoff, int k0) {
    const char* Ab = reinterpret_cast<const char*>(A_);
    const char* Bb = reinterpret_cast<const char*>(B_);
#pragma unroll
    for (int i = 0; i < BM / 32; ++i)
      gload16(Ab + (((size_t)(bm + i * 32 + rloc) * K + k0) << 1) + csrc,
              smem + dstoff + (i * 32 + w4 * 8) * 128);
#pragma unroll
    for (int i = 0; i < 4; ++i)
      gload16(Bb + (((size_t)(bn + i * 32 + rloc) * K + k0) << 1) + csrc,
              smem + dstoff + BM * 128 + (i * 32 + w4 * 8) * 128);
  };

  stageAB(0, 0);
  __syncthreads();

  int cur = 0;
  for (int k0 = 0; k0 < K; k0 += 64) {
    if (k0 + 64 < K) stageAB((cur ^ 1) * PH, k0 + 64);
    const char* As = smem + cur * PH;
    const char* Bs = As + BM * 128;
    bf16x8 af[MF][2], bfr[4][2];
#pragma unroll
    for (int mi = 0; mi < MF; ++mi)
#pragma unroll
      for (int ks = 0; ks < 2; ++ks)
        af[mi][ks] = *reinterpret_cast<const bf16x8*>(
            As + (wm * (BM / 2) + mi * 16 + lm) * 128 + ((((uint)ks * 4 + lw) ^ sw) << 4));
#pragma unroll
    for (int ni = 0; ni < 4; ++ni)
#pragma unroll
      for (int ks = 0; ks < 2; ++ks)
        bfr[ni][ks] = *reinterpret_cast<const bf16x8*>(
            Bs + (wn * 64 + ni * 16 + lm) * 128 + ((((uint)ks * 4 + lw) ^ sw) << 4));
#pragma unroll
    for (int ks = 0; ks < 2; ++ks)
#pragma unroll
      for (int mi = 0; mi < MF; ++mi)
#pragma unroll
        for (int ni = 0; ni < 4; ++ni)
          acc[mi][ni] = mfma16<F16>(af[mi][ks], bfr[ni][ks], acc[mi][ni]);
    __syncthreads();
    cur ^= 1;
  }
#pragma unroll
  for (int mi = 0; mi < MF; ++mi)
#pragma unroll
    for (int ni = 0; ni < 4; ++ni) {
      f32x4 a = acc[mi][ni];
      const int row0 = bm + wm * (BM / 2) + mi * 16 + lw * 4;
      const int col  = bn + wn * 64 + ni * 16 + lm;
      if constexpr (BF16OUT) {
        ushort_t* Cb = (ushort_t*)Cv;
#pragma unroll
        for (int r = 0; r < 4; ++r)
          Cb[(size_t)(row0 + r) * N + col] = f2bf(a[r]);
      } else {
        float* Cf = (float*)Cv;
#pragma unroll
        for (int r = 0; r < 4; ++r)
          Cf[(size_t)(row0 + r) * N + col] = a[r];
      }
    }
}

// ---------------- K3: bf16 MFMA block-causal flash attention -----------------
// R11/R14-proven: 64-row q-tile pairs -> 512 blocks; 8 waves (2 k-split
// groups); 2-buf/group LDS-staged 2-phase pipeline; per-wave 2K P; LDS 80K ->
// 2 blocks/CU = 4 waves/SIMD. FROZEN (fused/direct-reg variants spill).
__global__ __launch_bounds__(512, 4) void attn_mfma_kernel(
    const ushort_t* __restrict__ qT, const ushort_t* __restrict__ kT,
    const ushort_t* __restrict__ vT, ushort_t* __restrict__ aout) {
  __shared__ __align__(16) char smem[81920];  // 4x16K KV bufs + 8x2K P
  const int tid = threadIdx.x;
  const int l  = tid & 63, w8 = tid >> 6;
  const int grp = w8 >> 2, w4 = w8 & 3;
  const int lm = l & 15, lw = l >> 4, l7 = l & 7, l3 = l >> 3;
  const uint wg = xcd_swz(blockIdx.y * gridDim.x + blockIdx.x,
                          gridDim.x * gridDim.y);
  const int bh = (int)(wg >> 4), b = bh >> 4, h = bh & 15;
  const int p = (int)(wg & 15);                // 0..15
  const int qbA = 31 - p, qbB = p;             // 64-row q-tile indices
  const int nkbA = ((qbA >> 2) + 1) * 4;       // 20..32
  const int nkbB = ((qbB >> 2) + 1) * 4;       // 4..16 (prefix of A's range)
  const int iters  = nkbA >> 1;                // per-group iterations
  const int bIters = nkbB >> 1;

  bf16x8 qf[2][2];                             // [tile][ks], 16 q-rows per wave
#pragma unroll
  for (int tq = 0; tq < 2; ++tq) {
    const size_t qrow0 = (size_t)bh * SEQ + (tq ? qbB : qbA) * 64 + w4 * 16;
#pragma unroll
    for (int ks = 0; ks < 2; ++ks)
      qf[tq][ks] = *reinterpret_cast<const bf16x8*>(
          qT + (qrow0 + lm) * HD + lw * 8 + ks * 32);
  }

  const char* kTb = reinterpret_cast<const char*>(kT + (size_t)bh * SEQ * HD);
  const char* vTb = reinterpret_cast<const char*>(vT + (size_t)bh * HD * SEQ);
  const uint rloc = (uint)(w4 * 8 + l3);
  const uint csrc = (uint)((l7 ^ l3) << 4);
  char* Pbase = smem + 65536 + w8 * 2048;

  float l_acc[2] = {};
  f32x4 oacc[2][4] = {};

  auto stage = [&](int kb, int bufidx) {
    const char* sK = kTb + ((size_t)(kb * 64) + rloc) * 128 + csrc;
    const char* sV = vTb + (size_t)rloc * (SEQ * 2) + (size_t)kb * 128 + csrc;
    char* dK = smem + (grp * 2 + bufidx) * 16384 + w4 * 1024;
    char* dV = dK + 8192;
    gload16(sK, dK);
    gload16(sK + 4096, dK + 4096);
    gload16(sV, dV);
    gload16(sV + (size_t)32 * SEQ * 2, dV + 4096);
  };

  auto phase = [&](const char* Kb, const char* Vb, const bf16x8 (&qft)[2],
                   float& lat, f32x4 (&oat)[4]) {
    bf16x8 kf[2][4];
#pragma unroll
    for (int ks = 0; ks < 2; ++ks)
#pragma unroll
      for (int g = 0; g < 4; ++g)
        kf[ks][g] = *reinterpret_cast<const bf16x8*>(
            Kb + (g * 16 + lm) * 128 + ((lw * 16 + ks * 64) ^ (l7 << 4)));
    f32x4 st[4] = {};
    __builtin_amdgcn_s_setprio(1);
#pragma unroll
    for (int ks = 0; ks < 2; ++ks)
#pragma unroll
      for (int g = 0; g < 4; ++g)
        st[g] = __builtin_amdgcn_mfma_f32_16x16x32_bf16(kf[ks][g], qft[ks], st[g], 0, 0, 0);
    __builtin_amdgcn_s_setprio(0);
#pragma unroll
    for (int g = 0; g < 4; ++g) {
      f32x4 s4 = st[g];
      float p0 = __builtin_amdgcn_exp2f(s4.x);
      float p1 = __builtin_amdgcn_exp2f(s4.y);
      float p2 = __builtin_amdgcn_exp2f(s4.z);
      float p3 = __builtin_amdgcn_exp2f(s4.w);
      lat += (p0 + p1) + (p2 + p3);
      uint off = (uint)(lm * 128 + ((g * 32 + lw * 8) ^ (l7 << 4)));
      *reinterpret_cast<uint*>(Pbase + off)     = pack_bf16(p0, p1);
      *reinterpret_cast<uint*>(Pbase + off + 4) = pack_bf16(p2, p3);
    }
    bf16x8 vf[2][4];
#pragma unroll
    for (int ks = 0; ks < 2; ++ks)
#pragma unroll
      for (int dn = 0; dn < 4; ++dn)
        vf[ks][dn] = *reinterpret_cast<const bf16x8*>(
            Vb + (dn * 16 + lm) * 128 + ((lw * 16 + ks * 64) ^ (l7 << 4)));
    bf16x8 pf[2];
#pragma unroll
    for (int ks = 0; ks < 2; ++ks)
      pf[ks] = *reinterpret_cast<const bf16x8*>(
          Pbase + lm * 128 + ((lw * 16 + ks * 64) ^ (l7 << 4)));
    __builtin_amdgcn_s_setprio(1);
#pragma unroll
    for (int ks = 0; ks < 2; ++ks)
#pragma unroll
      for (int dn = 0; dn < 4; ++dn)
        oat[dn] = __builtin_amdgcn_mfma_f32_16x16x32_bf16(vf[ks][dn], pf[ks], oat[dn], 0, 0, 0);
    __builtin_amdgcn_s_setprio(0);
  };

  stage(grp, 0);
  __syncthreads();
  int cur = 0;
  for (int i = 0; i < iters; ++i) {
    if (i + 1 < iters) stage(2 * (i + 1) + grp, cur ^ 1);
    const char* Kb = smem + (grp * 2 + cur) * 16384;
    const char* Vb = Kb + 8192;
    phase(Kb, Vb, qf[0], l_acc[0], oacc[0]);
    if (i < bIters) phase(Kb, Vb, qf[1], l_acc[1], oacc[1]);
    __syncthreads();   // drains vmcnt(0): next tile staged; cur readers done
    cur ^= 1;
  }

  // merge group partials: group1 -> LDS (KV region dead), group0 adds.
  if (grp == 1) {
#pragma unroll
    for (int tq = 0; tq < 2; ++tq)
#pragma unroll
      for (int dn = 0; dn < 4; ++dn)
        *reinterpret_cast<f32x4*>(
            smem + (tq * 4 + dn) * 4096 + (w4 * 64 + l) * 16) = oacc[tq][dn];
    float2 lv{l_acc[0], l_acc[1]};
    *reinterpret_cast<float2*>(smem + 32768 + (w4 * 64 + l) * 8) = lv;
  }
  __syncthreads();
  if (grp == 0) {
#pragma unroll
    for (int tq = 0; tq < 2; ++tq)
#pragma unroll
      for (int dn = 0; dn < 4; ++dn)
        oacc[tq][dn] += *reinterpret_cast<const f32x4*>(
            smem + (tq * 4 + dn) * 4096 + (w4 * 64 + l) * 16);
    float2 lv = *reinterpret_cast<const float2*>(smem + 32768 + (w4 * 64 + l) * 8);
    l_acc[0] += lv.x; l_acc[1] += lv.y;

#pragma unroll
    for (int tq = 0; tq < 2; ++tq) {
      const int qb = tq ? qbB : qbA;
      float ls = l_acc[tq];
      ls += __shfl_xor(ls, 16);
      ls += __shfl_xor(ls, 32);
      float inv = 1.f / ls;
      const int qg = qb * 64 + w4 * 16 + lm;
#pragma unroll
      for (int dn = 0; dn < 4; ++dn) {
        f32x4 o = oacc[tq][dn];
        o *= inv;
        size_t off = ((size_t)b * SEQ + qg) * DIM + h * HD + dn * 16 + lw * 4;
        uint2 uo{(uint)f2h(o[0]) | ((uint)f2h(o[1]) << 16),
                 (uint)f2h(o[2]) | ((uint)f2h(o[3]) << 16)};
        *reinterpret_cast<uint2*>(&aout[off]) = uo;
      }
    }
  }
}

// ---------------- launch -----------------------------------------------------
extern "C" void kernel_launch(void* const* d_in, const int* in_sizes, int n_in,
                              void* d_out, int out_size, void* d_ws, size_t ws_size,
                              hipStream_t stream) {
  const float* x       = (const float*)d_in[0];
  const float* Wqkv    = (const float*)d_in[1];
  const float* Wout    = (const float*)d_in[2];
  const float* q_scale = (const float*)d_in[3];
  const float* k_scale = (const float*)d_in[4];
  float* out = (float*)d_out;

  char* ws = (char*)d_ws;
  ushort_t* attn_f16 = (ushort_t*)ws;
  size_t off = (size_t)MROW * N3 * 2;
  ushort_t* qT = (ushort_t*)(ws + off); off += (size_t)NB * NH * SEQ * HD * 2;
  ushort_t* kT = (ushort_t*)(ws + off); off += (size_t)NB * NH * SEQ * HD * 2;
  ushort_t* vT = (ushort_t*)(ws + off); off += (size_t)NB * NH * SEQ * HD * 2;
  float* tab   = (float*)(ws + off);    off += (size_t)SEQ * 64 * 4;
  ushort_t* xh   = (ushort_t*)(ws + off); off += (size_t)MROW * DIM * 2;
  ushort_t* wqh  = (ushort_t*)(ws + off); off += (size_t)N3 * DIM * 2;
  ushort_t* wo16 = (ushort_t*)(ws + off);

  prep_kernel<<<dim3(MROW * DIM / 4 / 256), dim3(256), 0, stream>>>(
      x, Wqkv, Wout, xh, wqh, wo16, tab);
  gemm_qkv_kernel<<<dim3(N3 / 256, MROW / 256), dim3(512), 0, stream>>>(
      xh, wqh, q_scale, k_scale, tab, qT, kT, vT);
  attn_mfma_kernel<<<dim3(16, NB * NH), dim3(512), 0, stream>>>(qT, kT, vT, attn_f16);
  gemm_mfma_kernel<128, false, true><<<dim3(DIM / 128, MROW / 128), dim3(256), 0, stream>>>(
      attn_f16, wo16, out, DIM, DIM);
}

// Round 18
// 97.415 us; speedup vs baseline: 1.0253x; 1.0253x over previous
//
#include <hip/hip_runtime.h>
#include <hip/hip_bf16.h>
#include <cstddef>

typedef unsigned int uint;
typedef unsigned short ushort_t;
typedef __attribute__((ext_vector_type(8))) short bf16x8;
typedef __attribute__((ext_vector_type(8))) _Float16 f16x8;
typedef __attribute__((ext_vector_type(4))) float f32x4;

constexpr int NB   = 2;
constexpr int NP   = 256;
constexpr int DIM  = 1024;
constexpr int NH   = 16;
constexpr int HD   = 64;
constexpr int SEQ  = 2048;
constexpr int MROW = NB * SEQ;      // 4096
constexpr int N3   = 3 * DIM;       // 3072
// softmax in base-2: fold hd^-0.5 * log2(e) into q
constexpr float QS = 0.125f * 1.4426950408889634f;

__device__ __forceinline__ ushort_t f2bf(float x) {
  uint u = __builtin_bit_cast(uint, x);
  u = (u + 0x7fff + ((u >> 16) & 1)) >> 16;   // round-to-nearest-even
  return (ushort_t)u;
}
__device__ __forceinline__ uint pack_bf16(float a, float b) {
  __hip_bfloat162 h = __float22bfloat162_rn(float2{a, b});
  uint u; __builtin_memcpy(&u, &h, 4);        // v_cvt_pk_bf16_f32
  return u;
}
__device__ __forceinline__ float bf2f(ushort_t h) {
  return __builtin_bit_cast(float, (uint)h << 16);
}
__device__ __forceinline__ ushort_t f2h(float x) {
  _Float16 h = (_Float16)x;
  ushort_t u; __builtin_memcpy(&u, &h, 2);
  return u;
}

template<bool F16>
__device__ __forceinline__ f32x4 mfma16(bf16x8 a, bf16x8 b, f32x4 c) {
  if constexpr (F16) {
    f16x8 af = __builtin_bit_cast(f16x8, a);
    f16x8 bf = __builtin_bit_cast(f16x8, b);
    return __builtin_amdgcn_mfma_f32_16x16x32_f16(af, bf, c, 0, 0, 0);
  } else {
    return __builtin_amdgcn_mfma_f32_16x16x32_bf16(a, b, c, 0, 0, 0);
  }
}

__device__ __forceinline__ void gload16(const void* g, void* l) {
  __builtin_amdgcn_global_load_lds((const __attribute__((address_space(1))) uint*)g,
                                   (__attribute__((address_space(3))) uint*)l, 16, 0, 0);
}

// XCD-aware bijective swizzle (valid when nwg % 8 == 0)
__device__ __forceinline__ uint xcd_swz(uint bid, uint nwg) {
  return (bid & 7) * (nwg >> 3) + (bid >> 3);
}

// ---------------- K0: fused prep: cvt x->bf16, Wqkv->bf16, Wout->f16, RoPE tab
__global__ __launch_bounds__(256) void prep_kernel(
    const float* __restrict__ x, const float* __restrict__ Wqkv,
    const float* __restrict__ Wout, ushort_t* __restrict__ xh,
    ushort_t* __restrict__ wqh, ushort_t* __restrict__ wo16,
    float* __restrict__ tab) {
  const int i = blockIdx.x * 256 + threadIdx.x;
  constexpr int NX = MROW * DIM / 4;   // 1048576
  constexpr int NQ = N3 * DIM / 4;     // 786432
  constexpr int NO = DIM * DIM / 4;    // 262144
  if (i < NX) {
    float4 v = reinterpret_cast<const float4*>(x)[i];
    uint2 o; o.x = pack_bf16(v.x, v.y); o.y = pack_bf16(v.z, v.w);
    reinterpret_cast<uint2*>(xh)[i] = o;
  }
  if (i < NQ) {
    float4 v = reinterpret_cast<const float4*>(Wqkv)[i];
    uint2 o; o.x = pack_bf16(v.x, v.y); o.y = pack_bf16(v.z, v.w);
    reinterpret_cast<uint2*>(wqh)[i] = o;
  }
  if (i < NO) {
    float4 v = reinterpret_cast<const float4*>(Wout)[i];
    uint2 o;
    o.x = (uint)f2h(v.x) | ((uint)f2h(v.y) << 16);
    o.y = (uint)f2h(v.z) | ((uint)f2h(v.w) << 16);
    reinterpret_cast<uint2*>(wo16)[i] = o;
  }
  if (i < SEQ * 32) {
    int l = i >> 5, ii = i & 31;
    float j = (float)(ii & 15);
    float invf = exp2f(-j * (13.287712379549449f / 16.f));
    float pos = (ii < 16) ? (float)(l >> 8) : (float)(l & (NP - 1));
    float ang = pos * invf;
    tab[i]            = cosf(ang);
    tab[SEQ * 32 + i] = sinf(ang);
  }
}

// ---------------- K1: QKV GEMM with FUSED RMSNorm+RoPE+transpose epilogue ----
__global__ __launch_bounds__(256) void gemm_qkv_kernel(
    const ushort_t* __restrict__ A_, const ushort_t* __restrict__ B_,
    const float* __restrict__ qs, const float* __restrict__ ksc,
    const float* __restrict__ tab, ushort_t* __restrict__ qT,
    ushort_t* __restrict__ kT, ushort_t* __restrict__ vT) {
  constexpr int BM = 128, K = DIM;
  constexpr int PH = (BM + 128) * 128;      // bytes per phase
  __shared__ __align__(16) char smem[2 * PH];
  const int tid = threadIdx.x;
  const int l = tid & 63, w4 = tid >> 6;
  const int l7 = l & 7, l3 = l >> 3, lm = l & 15, lw = l >> 4;
  const int wm = w4 >> 1, wn = w4 & 1;
  const uint nwg = gridDim.x * gridDim.y;
  const uint wg = xcd_swz(blockIdx.y * gridDim.x + blockIdx.x, nwg);
  const int bm = (int)(wg / gridDim.x) * BM, bn = (int)(wg % gridDim.x) * 128;
  const uint rloc = (uint)(w4 * 8 + l3);
  const uint csrc = (uint)((l7 ^ l3) << 4);
  const uint sw = (uint)(lm & 7);

  f32x4 acc[4][4] = {};

  auto stageAB = [&](int dstoff, int k0) {
    const char* Ab = reinterpret_cast<const char*>(A_);
    const char* Bb = reinterpret_cast<const char*>(B_);
#pragma unroll
    for (int i = 0; i < 4; ++i)
      gload16(Ab + (((size_t)(bm + i * 32 + rloc) * K + k0) << 1) + csrc,
              smem + dstoff + (i * 32 + w4 * 8) * 128);
#pragma unroll
    for (int i = 0; i < 4; ++i)
      gload16(Bb + (((size_t)(bn + i * 32 + rloc) * K + k0) << 1) + csrc,
              smem + dstoff + BM * 128 + (i * 32 + w4 * 8) * 128);
  };

  stageAB(0, 0);
  __syncthreads();
  int cur = 0;
  for (int k0 = 0; k0 < K; k0 += 64) {
    if (k0 + 64 < K) stageAB((cur ^ 1) * PH, k0 + 64);
    const char* As = smem + cur * PH;
    const char* Bs = As + BM * 128;
    bf16x8 af[4][2], bfr[4][2];
#pragma unroll
    for (int mi = 0; mi < 4; ++mi)
#pragma unroll
      for (int ks = 0; ks < 2; ++ks)
        af[mi][ks] = *reinterpret_cast<const bf16x8*>(
            As + (wm * 64 + mi * 16 + lm) * 128 + ((((uint)ks * 4 + lw) ^ sw) << 4));
#pragma unroll
    for (int ni = 0; ni < 4; ++ni)
#pragma unroll
      for (int ks = 0; ks < 2; ++ks)
        bfr[ni][ks] = *reinterpret_cast<const bf16x8*>(
            Bs + (wn * 64 + ni * 16 + lm) * 128 + ((((uint)ks * 4 + lw) ^ sw) << 4));
#pragma unroll
    for (int ks = 0; ks < 2; ++ks)
#pragma unroll
      for (int mi = 0; mi < 4; ++mi)
#pragma unroll
        for (int ni = 0; ni < 4; ++ni)
          acc[mi][ni] = __builtin_amdgcn_mfma_f32_16x16x32_bf16(
              af[mi][ks], bfr[ni][ks], acc[mi][ni], 0, 0, 0);
    __syncthreads();
    cur ^= 1;
  }

  const int sel = bn >> 10;                      // 0=q, 1=k, 2=v
  const int b   = bm >> 11;
  const int l0  = bm & (SEQ - 1);

  if (sel < 2) {
    const float* sc = (sel == 0) ? qs : ksc;
    ushort_t* dst   = (sel == 0) ? qT : kT;
    const int h   = ((bn & (DIM - 1)) >> 6) + wn;
    const int bhI = b * NH + h;
    float scv[4];
#pragma unroll
    for (int ni = 0; ni < 4; ++ni) scv[ni] = sc[ni * 16 + lm];
#pragma unroll
    for (int mi = 0; mi < 4; ++mi)
#pragma unroll
      for (int r = 0; r < 4; ++r) {
        const int lg = l0 + wm * 64 + mi * 16 + lw * 4 + r;
        float c0 = acc[mi][0][r], c1 = acc[mi][1][r];
        float c2 = acc[mi][2][r], c3 = acc[mi][3][r];
        float s = c0 * c0 + c1 * c1 + c2 * c2 + c3 * c3;
        s += __shfl_xor(s, 1); s += __shfl_xor(s, 2);
        s += __shfl_xor(s, 4); s += __shfl_xor(s, 8);
        float rms = rsqrtf(s * (1.f / HD) + 1e-6f);
        float cv[4] = {c0, c1, c2, c3};
#pragma unroll
        for (int ni = 0; ni < 4; ++ni) {
          float n  = cv[ni] * rms * scv[ni];
          float pr = __shfl_xor(n, 1);
          const int j = ni * 8 + (lm >> 1);
          float cz = tab[lg * 32 + j];
          float sz = tab[SEQ * 32 + lg * 32 + j];
          float o = (lm & 1) ? (pr * sz + n * cz) : (n * cz - pr * sz);
          if (sel == 0) o *= QS;
          dst[((size_t)bhI * SEQ + lg) * HD + ni * 16 + lm] = f2bf(o);
        }
      }
  } else {
    // v: stage bf16 into LDS [128][132], then transposed coalesced store
    ushort_t* vt = reinterpret_cast<ushort_t*>(smem);
#pragma unroll
    for (int mi = 0; mi < 4; ++mi)
#pragma unroll
      for (int ni = 0; ni < 4; ++ni)
#pragma unroll
        for (int r = 0; r < 4; ++r)
          vt[(wm * 64 + mi * 16 + lw * 4 + r) * 132 + wn * 64 + ni * 16 + lm] =
              f2bf(acc[mi][ni][r]);
    __syncthreads();
    const int d = tid >> 1, lc0 = (tid & 1) * 64;
    const int hv  = ((bn & (DIM - 1)) >> 6) + (d >> 6);
    const int dl  = d & 63;
    ushort_t* vp = vT + ((size_t)(b * NH + hv) * HD + dl) * SEQ + l0 + lc0;
#pragma unroll
    for (int u = 0; u < 8; ++u) {
      ushort_t t[8];
#pragma unroll
      for (int j = 0; j < 8; ++j) t[j] = vt[(lc0 + u * 8 + j) * 132 + d];
      uint4 w;
      w.x = (uint)t[0] | ((uint)t[1] << 16);
      w.y = (uint)t[2] | ((uint)t[3] << 16);
      w.z = (uint)t[4] | ((uint)t[5] << 16);
      w.w = (uint)t[6] | ((uint)t[7] << 16);
      reinterpret_cast<uint4*>(vp)[u] = w;
    }
  }
}

// ---------------- generic 16-bit MFMA GEMM (out-projection) ------------------
template<int BM, bool BF16OUT, bool F16>
__global__ __launch_bounds__(256) void gemm_mfma_kernel(
    const ushort_t* __restrict__ A_, const ushort_t* __restrict__ B_,
    void* __restrict__ Cv, int N, int K) {
  constexpr int MF = BM / 32;
  constexpr int PH = (BM + 128) * 128;
  __shared__ __align__(16) char smem[2 * PH];
  const int tid = threadIdx.x;
  const int l = tid & 63, w4 = tid >> 6;
  const int l7 = l & 7, l3 = l >> 3, lm = l & 15, lw = l >> 4;
  const int wm = w4 >> 1, wn = w4 & 1;
  const uint nwg = gridDim.x * gridDim.y;
  const uint wg = xcd_swz(blockIdx.y * gridDim.x + blockIdx.x, nwg);
  const int bm = (int)(wg / gridDim.x) * BM, bn = (int)(wg % gridDim.x) * 128;
  const uint rloc = (uint)(w4 * 8 + l3);
  const uint csrc = (uint)((l7 ^ l3) << 4);
  const uint sw = (uint)(lm & 7);

  f32x4 acc[MF][4] = {};

  auto stageAB = [&](int dstoff, int k0) {
    const char* Ab = reinterpret_cast<const char*>(A_);
    const char* Bb = reinterpret_cast<const char*>(B_);
#pragma unroll
    for (int i = 0; i < BM / 32; ++i)
      gload16(Ab + (((size_t)(bm + i * 32 + rloc) * K + k0) << 1) + csrc,
              smem + dstoff + (i * 32 + w4 * 8) * 128);
#pragma unroll
    for (int i = 0; i < 4; ++i)
      gload16(Bb + (((size_t)(bn + i * 32 + rloc) * K + k0) << 1) + csrc,
              smem + dstoff + BM * 128 + (i * 32 + w4 * 8) * 128);
  };

  stageAB(0, 0);
  __syncthreads();

  int cur = 0;
  for (int k0 = 0; k0 < K; k0 += 64) {
    if (k0 + 64 < K) stageAB((cur ^ 1) * PH, k0 + 64);
    const char* As = smem + cur * PH;
    const char* Bs = As + BM * 128;
    bf16x8 af[MF][2], bfr[4][2];
#pragma unroll
    for (int mi = 0; mi < MF; ++mi)
#pragma unroll
      for (int ks = 0; ks < 2; ++ks)
        af[mi][ks] = *reinterpret_cast<const bf16x8*>(
            As + (wm * (BM / 2) + mi * 16 + lm) * 128 + ((((uint)ks * 4 + lw) ^ sw) << 4));
#pragma unroll
    for (int ni = 0; ni < 4; ++ni)
#pragma unroll
      for (int ks = 0; ks < 2; ++ks)
        bfr[ni][ks] = *reinterpret_cast<const bf16x8*>(
            Bs + (wn * 64 + ni * 16 + lm) * 128 + ((((uint)ks * 4 + lw) ^ sw) << 4));
#pragma unroll
    for (int ks = 0; ks < 2; ++ks)
#pragma unroll
      for (int mi = 0; mi < MF; ++mi)
#pragma unroll
        for (int ni = 0; ni < 4; ++ni)
          acc[mi][ni] = mfma16<F16>(af[mi][ks], bfr[ni][ks], acc[mi][ni]);
    __syncthreads();
    cur ^= 1;
  }
#pragma unroll
  for (int mi = 0; mi < MF; ++mi)
#pragma unroll
    for (int ni = 0; ni < 4; ++ni) {
      f32x4 a = acc[mi][ni];
      const int row0 = bm + wm * (BM / 2) + mi * 16 + lw * 4;
      const int col  = bn + wn * 64 + ni * 16 + lm;
      if constexpr (BF16OUT) {
        ushort_t* Cb = (ushort_t*)Cv;
#pragma unroll
        for (int r = 0; r < 4; ++r)
          Cb[(size_t)(row0 + r) * N + col] = f2bf(a[r]);
      } else {
        float* Cf = (float*)Cv;
#pragma unroll
        for (int r = 0; r < 4; ++r)
          Cf[(size_t)(row0 + r) * N + col] = a[r];
      }
    }
}

// ---------------- K3: bf16 MFMA block-causal flash attention -----------------
// R11/R14-proven: 64-row q-tile pairs -> 512 blocks; 8 waves (2 k-split
// groups); 2-buf/group LDS-staged 2-phase pipeline; per-wave 2K P; LDS 80K ->
// 2 blocks/CU = 4 waves/SIMD. FROZEN (fused/direct-reg variants spill).
__global__ __launch_bounds__(512, 4) void attn_mfma_kernel(
    const ushort_t* __restrict__ qT, const ushort_t* __restrict__ kT,
    const ushort_t* __restrict__ vT, ushort_t* __restrict__ aout) {
  __shared__ __align__(16) char smem[81920];  // 4x16K KV bufs + 8x2K P
  const int tid = threadIdx.x;
  const int l  = tid & 63, w8 = tid >> 6;
  const int grp = w8 >> 2, w4 = w8 & 3;
  const int lm = l & 15, lw = l >> 4, l7 = l & 7, l3 = l >> 3;
  const uint wg = xcd_swz(blockIdx.y * gridDim.x + blockIdx.x,
                          gridDim.x * gridDim.y);
  const int bh = (int)(wg >> 4), b = bh >> 4, h = bh & 15;
  const int p = (int)(wg & 15);                // 0..15
  const int qbA = 31 - p, qbB = p;             // 64-row q-tile indices
  const int nkbA = ((qbA >> 2) + 1) * 4;       // 20..32
  const int nkbB = ((qbB >> 2) + 1) * 4;       // 4..16 (prefix of A's range)
  const int iters  = nkbA >> 1;                // per-group iterations
  const int bIters = nkbB >> 1;

  bf16x8 qf[2][2];                             // [tile][ks], 16 q-rows per wave
#pragma unroll
  for (int tq = 0; tq < 2; ++tq) {
    const size_t qrow0 = (size_t)bh * SEQ + (tq ? qbB : qbA) * 64 + w4 * 16;
#pragma unroll
    for (int ks = 0; ks < 2; ++ks)
      qf[tq][ks] = *reinterpret_cast<const bf16x8*>(
          qT + (qrow0 + lm) * HD + lw * 8 + ks * 32);
  }

  const char* kTb = reinterpret_cast<const char*>(kT + (size_t)bh * SEQ * HD);
  const char* vTb = reinterpret_cast<const char*>(vT + (size_t)bh * HD * SEQ);
  const uint rloc = (uint)(w4 * 8 + l3);
  const uint csrc = (uint)((l7 ^ l3) << 4);
  char* Pbase = smem + 65536 + w8 * 2048;

  float l_acc[2] = {};
  f32x4 oacc[2][4] = {};

  auto stage = [&](int kb, int bufidx) {
    const char* sK = kTb + ((size_t)(kb * 64) + rloc) * 128 + csrc;
    const char* sV = vTb + (size_t)rloc * (SEQ * 2) + (size_t)kb * 128 + csrc;
    char* dK = smem + (grp * 2 + bufidx) * 16384 + w4 * 1024;
    char* dV = dK + 8192;
    gload16(sK, dK);
    gload16(sK + 4096, dK + 4096);
    gload16(sV, dV);
    gload16(sV + (size_t)32 * SEQ * 2, dV + 4096);
  };

  auto phase = [&](const char* Kb, const char* Vb, const bf16x8 (&qft)[2],
                   float& lat, f32x4 (&oat)[4]) {
    bf16x8 kf[2][4];
#pragma unroll
    for (int ks = 0; ks < 2; ++ks)
#pragma unroll
      for (int g = 0; g < 4; ++g)
        kf[ks][g] = *reinterpret_cast<const bf16x8*>(
            Kb + (g * 16 + lm) * 128 + ((lw * 16 + ks * 64) ^ (l7 << 4)));
    f32x4 st[4] = {};
    __builtin_amdgcn_s_setprio(1);
#pragma unroll
    for (int ks = 0; ks < 2; ++ks)
#pragma unroll
      for (int g = 0; g < 4; ++g)
        st[g] = __builtin_amdgcn_mfma_f32_16x16x32_bf16(kf[ks][g], qft[ks], st[g], 0, 0, 0);
    __builtin_amdgcn_s_setprio(0);
#pragma unroll
    for (int g = 0; g < 4; ++g) {
      f32x4 s4 = st[g];
      float p0 = __builtin_amdgcn_exp2f(s4.x);
      float p1 = __builtin_amdgcn_exp2f(s4.y);
      float p2 = __builtin_amdgcn_exp2f(s4.z);
      float p3 = __builtin_amdgcn_exp2f(s4.w);
      lat += (p0 + p1) + (p2 + p3);
      uint off = (uint)(lm * 128 + ((g * 32 + lw * 8) ^ (l7 << 4)));
      *reinterpret_cast<uint*>(Pbase + off)     = pack_bf16(p0, p1);
      *reinterpret_cast<uint*>(Pbase + off + 4) = pack_bf16(p2, p3);
    }
    bf16x8 vf[2][4];
#pragma unroll
    for (int ks = 0; ks < 2; ++ks)
#pragma unroll
      for (int dn = 0; dn < 4; ++dn)
        vf[ks][dn] = *reinterpret_cast<const bf16x8*>(
            Vb + (dn * 16 + lm) * 128 + ((lw * 16 + ks * 64) ^ (l7 << 4)));
    bf16x8 pf[2];
#pragma unroll
    for (int ks = 0; ks < 2; ++ks)
      pf[ks] = *reinterpret_cast<const bf16x8*>(
          Pbase + lm * 128 + ((lw * 16 + ks * 64) ^ (l7 << 4)));
    __builtin_amdgcn_s_setprio(1);
#pragma unroll
    for (int ks = 0; ks < 2; ++ks)
#pragma unroll
      for (int dn = 0; dn < 4; ++dn)
        oat[dn] = __builtin_amdgcn_mfma_f32_16x16x32_bf16(vf[ks][dn], pf[ks], oat[dn], 0, 0, 0);
    __builtin_amdgcn_s_setprio(0);
  };

  stage(grp, 0);
  __syncthreads();
  int cur = 0;
  for (int i = 0; i < iters; ++i) {
    if (i + 1 < iters) stage(2 * (i + 1) + grp, cur ^ 1);
    const char* Kb = smem + (grp * 2 + cur) * 16384;
    const char* Vb = Kb + 8192;
    phase(Kb, Vb, qf[0], l_acc[0], oacc[0]);
    if (i < bIters) phase(Kb, Vb, qf[1], l_acc[1], oacc[1]);
    __syncthreads();   // drains vmcnt(0): next tile staged; cur readers done
    cur ^= 1;
  }

  // merge group partials: group1 -> LDS (KV region dead), group0 adds.
  if (grp == 1) {
#pragma unroll
    for (int tq = 0; tq < 2; ++tq)
#pragma unroll
      for (int dn = 0; dn < 4; ++dn)
        *reinterpret_cast<f32x4*>(
            smem + (tq * 4 + dn) * 4096 + (w4 * 64 + l) * 16) = oacc[tq][dn];
    float2 lv{l_acc[0], l_acc[1]};
    *reinterpret_cast<float2*>(smem + 32768 + (w4 * 64 + l) * 8) = lv;
  }
  __syncthreads();
  if (grp == 0) {
#pragma unroll
    for (int tq = 0; tq < 2; ++tq)
#pragma unroll
      for (int dn = 0; dn < 4; ++dn)
        oacc[tq][dn] += *reinterpret_cast<const f32x4*>(
            smem + (tq * 4 + dn) * 4096 + (w4 * 64 + l) * 16);
    float2 lv = *reinterpret_cast<const float2*>(smem + 32768 + (w4 * 64 + l) * 8);
    l_acc[0] += lv.x; l_acc[1] += lv.y;

#pragma unroll
    for (int tq = 0; tq < 2; ++tq) {
      const int qb = tq ? qbB : qbA;
      float ls = l_acc[tq];
      ls += __shfl_xor(ls, 16);
      ls += __shfl_xor(ls, 32);
      float inv = 1.f / ls;
      const int qg = qb * 64 + w4 * 16 + lm;
#pragma unroll
      for (int dn = 0; dn < 4; ++dn) {
        f32x4 o = oacc[tq][dn];
        o *= inv;
        size_t off = ((size_t)b * SEQ + qg) * DIM + h * HD + dn * 16 + lw * 4;
        uint2 uo{(uint)f2h(o[0]) | ((uint)f2h(o[1]) << 16),
                 (uint)f2h(o[2]) | ((uint)f2h(o[3]) << 16)};
        *reinterpret_cast<uint2*>(&aout[off]) = uo;
      }
    }
  }
}

// ---------------- launch -----------------------------------------------------
extern "C" void kernel_launch(void* const* d_in, const int* in_sizes, int n_in,
                              void* d_out, int out_size, void* d_ws, size_t ws_size,
                              hipStream_t stream) {
  const float* x       = (const float*)d_in[0];
  const float* Wqkv    = (const float*)d_in[1];
  const float* Wout    = (const float*)d_in[2];
  const float* q_scale = (const float*)d_in[3];
  const float* k_scale = (const float*)d_in[4];
  float* out = (float*)d_out;

  char* ws = (char*)d_ws;
  ushort_t* attn_f16 = (ushort_t*)ws;
  size_t off = (size_t)MROW * N3 * 2;
  ushort_t* qT = (ushort_t*)(ws + off); off += (size_t)NB * NH * SEQ * HD * 2;
  ushort_t* kT = (ushort_t*)(ws + off); off += (size_t)NB * NH * SEQ * HD * 2;
  ushort_t* vT = (ushort_t*)(ws + off); off += (size_t)NB * NH * SEQ * HD * 2;
  float* tab   = (float*)(ws + off);    off += (size_t)SEQ * 64 * 4;
  ushort_t* xh   = (ushort_t*)(ws + off); off += (size_t)MROW * DIM * 2;
  ushort_t* wqh  = (ushort_t*)(ws + off); off += (size_t)N3 * DIM * 2;
  ushort_t* wo16 = (ushort_t*)(ws + off);

  prep_kernel<<<dim3(MROW * DIM / 4 / 256), dim3(256), 0, stream>>>(
      x, Wqkv, Wout, xh, wqh, wo16, tab);
  gemm_qkv_kernel<<<dim3(N3 / 128, MROW / 128), dim3(256), 0, stream>>>(
      xh, wqh, q_scale, k_scale, tab, qT, kT, vT);
  attn_mfma_kernel<<<dim3(16, NB * NH), dim3(512), 0, stream>>>(qT, kT, vT, attn_f16);
  gemm_mfma_kernel<128, false, true><<<dim3(DIM / 128, MROW / 128), dim3(256), 0, stream>>>(
      attn_f16, wo16, out, DIM, DIM);
}